// Round 1
// 295.680 us; speedup vs baseline: 1.1280x; 1.1280x over previous
//
#include <hip/hip_runtime.h>
#include <float.h>

#define N_PART 262144
#define GRID_DIM 256
#define NUM_CELLS (GRID_DIM * GRID_DIM)
#define KSLOT 32
#define MAXNB 64

// ---------------- ws layout (all 256B-aligned) ----------------
// params     : 3 uints (min x bits, min y bits, max h bits)
// counts     : NUM_CELLS ints          (zeroed)
// cursor     : NUM_CELLS ints          (zeroed, scatter cursors)
// chunkSums  : 256 ints
// starts     : NUM_CELLS+2 ints        (CSR row starts; [NC]=[NC+1]=N)
// lin        : N ints                  (cell of each particle)
// sid        : N+64 ints               (particle ids, cell-major, id-sorted)
// linS       : N ints                  (cell of rank r)
// Q          : (N+64) float4           ({x, y, id-as-float-bits, sup})

__global__ void init_params(unsigned int* params) {
    params[0] = 0x7f7fffffu;  // FLT_MAX bits (min x)
    params[1] = 0x7f7fffffu;  // FLT_MAX bits (min y)
    params[2] = 0u;           // 0.0f       (max h)
}

__global__ void reduce_kernel(const float* __restrict__ pos,
                              const float* __restrict__ sup,
                              unsigned int* params, int n) {
    __shared__ unsigned int s_minx, s_miny, s_maxh;
    if (threadIdx.x == 0) { s_minx = 0x7f7fffffu; s_miny = 0x7f7fffffu; s_maxh = 0u; }
    __syncthreads();
    float mx = FLT_MAX, my = FLT_MAX, mh = 0.0f;
    for (int i = blockIdx.x * blockDim.x + threadIdx.x; i < n;
         i += gridDim.x * blockDim.x) {
        float x = pos[2 * i], y = pos[2 * i + 1], h = sup[i];
        mx = fminf(mx, x);
        my = fminf(my, y);
        mh = fmaxf(mh, h);
    }
    // non-negative floats: uint compare == float compare
    atomicMin(&s_minx, __float_as_uint(mx));
    atomicMin(&s_miny, __float_as_uint(my));
    atomicMax(&s_maxh, __float_as_uint(mh));
    __syncthreads();
    if (threadIdx.x == 0) {
        atomicMin(&params[0], s_minx);
        atomicMin(&params[1], s_miny);
        atomicMax(&params[2], s_maxh);
    }
}

__global__ void bin_kernel(const float* __restrict__ pos,
                           const unsigned int* __restrict__ params,
                           int* __restrict__ counts, int* __restrict__ lin_out,
                           int n) {
    int i = blockIdx.x * blockDim.x + threadIdx.x;
    if (i >= n) return;
    float hmax  = __uint_as_float(params[2]);
    float qminx = __uint_as_float(params[0]) - hmax;
    float qminy = __uint_as_float(params[1]) - hmax;
    float x = pos[2 * i], y = pos[2 * i + 1];
    int cx = (int)ceilf((x - qminx) / hmax);
    int cy = (int)ceilf((y - qminy) / hmax);
    cx = min(max(cx, 0), GRID_DIM - 1);
    cy = min(max(cy, 0), GRID_DIM - 1);
    int lin = cx + GRID_DIM * cy;
    lin_out[i] = lin;
    atomicAdd(&counts[lin], 1);
}

// exclusive scan of 65536 counts: per-256-chunk local scan + chunk sums
__global__ void scan_local(const int* __restrict__ counts,
                           int* __restrict__ starts,
                           int* __restrict__ chunkSums) {
    __shared__ int sd[256];
    int t = threadIdx.x;
    int idx = blockIdx.x * 256 + t;
    int v = counts[idx];
    sd[t] = v;
    __syncthreads();
#pragma unroll
    for (int off = 1; off < 256; off <<= 1) {
        int x = (t >= off) ? sd[t - off] : 0;
        __syncthreads();
        sd[t] += x;
        __syncthreads();
    }
    starts[idx] = sd[t] - v;            // exclusive within chunk
    if (t == 255) chunkSums[blockIdx.x] = sd[t];
}

// each block sums chunkSums[0..b-1] (redundantly) and applies to its chunk
__global__ void scan_apply(int* __restrict__ starts,
                           const int* __restrict__ chunkSums, int n) {
    __shared__ int red[256];
    int t = threadIdx.x, b = blockIdx.x;
    red[t] = (t < b) ? chunkSums[t] : 0;
    __syncthreads();
#pragma unroll
    for (int s = 128; s > 0; s >>= 1) {
        if (t < s) red[t] += red[t + s];
        __syncthreads();
    }
    starts[b * 256 + t] += red[0];
    if (b == 255 && t == 0) {
        starts[NUM_CELLS]     = n;      // reference overflow row: empty
        starts[NUM_CELLS + 1] = n;
    }
}

__global__ void scatter_kernel(const int* __restrict__ lin,
                               const int* __restrict__ starts,
                               int* __restrict__ cursor,
                               int* __restrict__ sid, int n) {
    int i = blockIdx.x * blockDim.x + threadIdx.x;
    if (i >= n) return;
    int c = lin[i];
    int r = atomicAdd(&cursor[c], 1);   // arbitrary order; sorted next pass
    sid[starts[c] + r] = i;
}

// thread per cell: restore ascending-particle-id order (stable argsort
// semantics), then emit packed candidate records in rank order.
__global__ void sortseg_kernel(const int* __restrict__ starts,
                               int* __restrict__ sid,
                               int* __restrict__ linS,
                               float4* __restrict__ Q,
                               const float2* __restrict__ pos2,
                               const float* __restrict__ sup) {
    int c = blockIdx.x * blockDim.x + threadIdx.x;
    if (c >= NUM_CELLS) return;
    int b = starts[c], e = starts[c + 1];
    for (int a = b + 1; a < e; a++) {
        int v = sid[a];
        int k = a - 1;
        while (k >= b && sid[k] > v) { sid[k + 1] = sid[k]; k--; }
        sid[k + 1] = v;
    }
    for (int s = b; s < e; s++) {
        int j = sid[s];
        float2 pj = pos2[j];            // bitwise copy: query numerics identical
        Q[s] = make_float4(pj.x, pj.y, __int_as_float(j), sup[j]);
        linS[s] = c;
    }
}

// One wave per RANK (cell-sorted order): consecutive waves read overlapping
// dense CSR segments -> L1/L2 hits. All wave-uniform state forced to SGPRs
// via readfirstlane; lane->segment selection is a fully unrolled cndmask
// chain (no dynamically-indexed local arrays -> no scratch).
__global__ __launch_bounds__(256) void query_kernel(
        const int* __restrict__ linS, const float4* __restrict__ Q,
        const int* __restrict__ starts,
        float* __restrict__ outN, float* __restrict__ outC,
        float* __restrict__ outR, int n) {
#pragma clang fp contract(off)
    __shared__ int   s_id[4][MAXNB];
    __shared__ float s_d[4][MAXNB];

    int gtid = blockIdx.x * blockDim.x + threadIdx.x;
    int r    = gtid >> 6;              // rank in cell-sorted order
    int lane = threadIdx.x & 63;
    int wsl  = threadIdx.x >> 6;
    if (r >= n) return;

    float4 me = Q[r];
    int   i  = __builtin_amdgcn_readfirstlane(__float_as_int(me.z));
    float px = __int_as_float(__builtin_amdgcn_readfirstlane(__float_as_int(me.x)));
    float py = __int_as_float(__builtin_amdgcn_readfirstlane(__float_as_int(me.y)));
    float h  = __int_as_float(__builtin_amdgcn_readfirstlane(__float_as_int(me.w)));
    int   L  = __builtin_amdgcn_readfirstlane(linS[r]);

    // reference candidate-cell order: offs = dx + 256*dy, ij-meshgrid
    const int offs[9] = {-257, -1, 255, -256, 0, 256, -255, 1, 257};
    int cum[10], delta[9];
    cum[0] = 0;
#pragma unroll
    for (int o = 0; o < 9; o++) {
        int cell = L + offs[o];
        cell = min(max(cell, 0), NUM_CELLS);   // clip (duplicates at edges,
                                               //  exactly like the reference)
        int bb = __builtin_amdgcn_readfirstlane(starts[cell]);
        int ee = __builtin_amdgcn_readfirstlane(starts[cell + 1]);
        int cc = min(ee - bb, KSLOT);          // keep lowest-32 ids, as ref
        delta[o]  = bb - cum[o];               // idx = ll + delta[seg]
        cum[o + 1] = cum[o] + cc;
    }
    int T = cum[9];

    int total = 0;
    for (int b0 = 0; b0 < T; b0 += 64) {
        int ll = b0 + lane;
        int dsel = delta[0];
#pragma unroll
        for (int m = 1; m < 9; m++)
            dsel = (ll >= cum[m]) ? delta[m] : dsel;
        int idx = ll + dsel;                   // <= N+63: Q/sid padded by 64
        float4 q = Q[idx];
        float dx = q.x - px;
        float dy = q.y - py;
        float s2 = dx * dx + dy * dy;          // contract(off): match XLA
        float d  = sqrtf(s2);                  // correctly rounded
        bool valid = (ll < T) && (d <= h);     // NaN-safe for pad garbage
        unsigned long long bal = __ballot(valid);
        int rank = __popcll(bal & ((1ull << lane) - 1ull));
        if (valid) {
            int w = total + rank;
            if (w < MAXNB) {
                s_id[wsl][w] = __float_as_int(q.z);
                s_d[wsl][w]  = d;
            }
        }
        total += __popcll(bal);
    }

    // wave-private LDS buffer, same-wave DS ops are ordered: no barrier.
    int stored = min(total, MAXNB);
    size_t base = (size_t)i * MAXNB;           // 256B-aligned, fully written
    if (lane < stored) {
        int j   = s_id[wsl][lane];
        float d = s_d[wsl][lane];
        outN[base + lane] = (float)j;
        outR[base + lane] = d / h;
    } else {
        outN[base + lane] = -1.0f;
        outR[base + lane] = 0.0f;
    }
    if (lane == 0) outC[i] = (float)total;
}

extern "C" void kernel_launch(void* const* d_in, const int* in_sizes, int n_in,
                              void* d_out, int out_size, void* d_ws, size_t ws_size,
                              hipStream_t stream) {
    const float* pos = (const float*)d_in[0];
    const float* sup = (const float*)d_in[1];

    char* p = (char*)d_ws;
    auto alloc = [&](size_t bytes) {
        char* q = p;
        p += (bytes + 255) & ~(size_t)255;
        return q;
    };
    unsigned int* params    = (unsigned int*)alloc(256);
    int*          counts    = (int*)alloc((size_t)NUM_CELLS * 4);
    int*          cursor    = (int*)alloc((size_t)NUM_CELLS * 4);   // contiguous w/ counts
    int*          chunkSums = (int*)alloc(256 * 4);
    int*          starts    = (int*)alloc((size_t)(NUM_CELLS + 2) * 4);
    int*          lin       = (int*)alloc((size_t)N_PART * 4);
    int*          sid       = (int*)alloc((size_t)(N_PART + 64) * 4);
    int*          linS      = (int*)alloc((size_t)N_PART * 4);
    float4*       Q         = (float4*)alloc((size_t)(N_PART + 64) * 16);

    float* out  = (float*)d_out;
    float* outN = out;                              // N*64 neighbor ids (as f32)
    float* outC = out + (size_t)N_PART * MAXNB;     // N counts
    float* outR = outC + N_PART;                    // N*64 radial

    // counts+cursor are adjacent: one memset zeroes both
    hipMemsetAsync(counts, 0, (size_t)NUM_CELLS * 4 * 2, stream);
    init_params<<<1, 1, 0, stream>>>(params);
    reduce_kernel<<<256, 256, 0, stream>>>(pos, sup, params, N_PART);
    bin_kernel<<<N_PART / 256, 256, 0, stream>>>(pos, params, counts, lin, N_PART);
    scan_local<<<NUM_CELLS / 256, 256, 0, stream>>>(counts, starts, chunkSums);
    scan_apply<<<NUM_CELLS / 256, 256, 0, stream>>>(starts, chunkSums, N_PART);
    scatter_kernel<<<N_PART / 256, 256, 0, stream>>>(lin, starts, cursor, sid, N_PART);
    sortseg_kernel<<<NUM_CELLS / 256, 256, 0, stream>>>(starts, sid, linS, Q,
                                                        (const float2*)pos, sup);
    // one wave per rank: N_PART waves = N_PART*64 threads
    query_kernel<<<(N_PART * 64) / 256, 256, 0, stream>>>(
        linS, Q, starts, outN, outC, outR, N_PART);
}